// Round 9
// baseline (1737.158 us; speedup 1.0000x reference)
//
#include <hip/hip_runtime.h>
#include <math.h>

// Problem constants (fixed by reference setup_inputs)
#define N_NODES 262144      // S*T
#define SSTMT   16384
#define TT      16
#define DD      128
#define HH      3
#define HD      384         // H*D
#define EPSV    1e-5f

// swizzled physical column for logical 4-aligned col c in row `row`
__device__ __forceinline__ int swzc(int row, int c) { return c ^ (((row >> 3) & 3) << 2); }

// ---------------------------------------------------------------------------
// stage a [64][128] fp32 tile from global into swizzled LDS layout
// ---------------------------------------------------------------------------
template<int NTHR>
__device__ __forceinline__ void stageSwz(float (*dst)[DD], const float* __restrict__ src)
{
    const int tid = threadIdx.x;
    #pragma unroll
    for (int j = 0; j < 2048 / NTHR; ++j) {
        int gi = j * NTHR + tid;
        int row = gi >> 5;
        int c4 = (gi & 31) * 4;
        *reinterpret_cast<float4*>(&dst[row][swzc(row, c4)]) =
            *reinterpret_cast<const float4*>(&src[(size_t)row * DD + c4]);
    }
}

// ---------------------------------------------------------------------------
// GEMM chunk: acc[i][j] += A[rr*8+i][kbeg+k] * B[kbeg+k][cg*8+j], k in [0,KLEN)
// A: swizzled LDS (broadcast b128 reads, conflict-free)
// B: GLOBAL, software-pipelined DOUBLE-BUFFER: next 4-k's 8 loads are issued
//    before the current 256 FMAs so L2 latency hides under compute.
// ---------------------------------------------------------------------------
#define LOADB8(buf, koff)                                                   \
    {   const float* _p = bp + (size_t)(koff) * BSTR;                       \
        buf[0] = *reinterpret_cast<const float4*>(_p);                      \
        buf[1] = *reinterpret_cast<const float4*>(_p + 4);                  \
        buf[2] = *reinterpret_cast<const float4*>(_p + BSTR);               \
        buf[3] = *reinterpret_cast<const float4*>(_p + BSTR + 4);           \
        buf[4] = *reinterpret_cast<const float4*>(_p + 2 * BSTR);           \
        buf[5] = *reinterpret_cast<const float4*>(_p + 2 * BSTR + 4);       \
        buf[6] = *reinterpret_cast<const float4*>(_p + 3 * BSTR);           \
        buf[7] = *reinterpret_cast<const float4*>(_p + 3 * BSTR + 4);       \
    }
#define LOADA8(buf, pc)                                                     \
    {   _Pragma("unroll")                                                   \
        for (int _i = 0; _i < 8; ++_i)                                      \
            buf[_i] = *reinterpret_cast<const float4*>(ar + _i * DD + (pc)); \
    }
#define FMAB8(abuf, bbuf)                                                   \
    {   _Pragma("unroll")                                                   \
        for (int _i = 0; _i < 8; ++_i) {                                    \
            float4 _a = abuf[_i];                                           \
            acc[_i][0] += _a.x*bbuf[0].x; acc[_i][1] += _a.x*bbuf[0].y;     \
            acc[_i][2] += _a.x*bbuf[0].z; acc[_i][3] += _a.x*bbuf[0].w;     \
            acc[_i][4] += _a.x*bbuf[1].x; acc[_i][5] += _a.x*bbuf[1].y;     \
            acc[_i][6] += _a.x*bbuf[1].z; acc[_i][7] += _a.x*bbuf[1].w;     \
            acc[_i][0] += _a.y*bbuf[2].x; acc[_i][1] += _a.y*bbuf[2].y;     \
            acc[_i][2] += _a.y*bbuf[2].z; acc[_i][3] += _a.y*bbuf[2].w;     \
            acc[_i][4] += _a.y*bbuf[3].x; acc[_i][5] += _a.y*bbuf[3].y;     \
            acc[_i][6] += _a.y*bbuf[3].z; acc[_i][7] += _a.y*bbuf[3].w;     \
            acc[_i][0] += _a.z*bbuf[4].x; acc[_i][1] += _a.z*bbuf[4].y;     \
            acc[_i][2] += _a.z*bbuf[4].z; acc[_i][3] += _a.z*bbuf[4].w;     \
            acc[_i][4] += _a.z*bbuf[5].x; acc[_i][5] += _a.z*bbuf[5].y;     \
            acc[_i][6] += _a.z*bbuf[5].z; acc[_i][7] += _a.z*bbuf[5].w;     \
            acc[_i][0] += _a.w*bbuf[6].x; acc[_i][1] += _a.w*bbuf[6].y;     \
            acc[_i][2] += _a.w*bbuf[6].z; acc[_i][3] += _a.w*bbuf[6].w;     \
            acc[_i][4] += _a.w*bbuf[7].x; acc[_i][5] += _a.w*bbuf[7].y;     \
            acc[_i][6] += _a.w*bbuf[7].z; acc[_i][7] += _a.w*bbuf[7].w;     \
        }                                                                   \
    }

template<int BSTR, int KLEN>
__device__ __forceinline__ void gemm8x8(const float (*A)[DD], const float* __restrict__ Bbase,
                                        int kbeg, int rr, int pad, float acc[8][8])
{
    const float* bp = Bbase + (size_t)kbeg * BSTR;
    const float* ar = &A[rr * 8][0];
    float4 bA[8], bB[8], aC[8];

    LOADB8(bA, 0);
    int k = 0;
    #pragma unroll 1
    for (; k < KLEN - 8; k += 8) {
        LOADB8(bB, k + 4);                 // prefetch second half-step
        LOADA8(aC, (kbeg + k) ^ pad);
        FMAB8(aC, bA);
        LOADB8(bA, k + 8);                 // prefetch next step's first half
        LOADA8(aC, (kbeg + k + 4) ^ pad);
        FMAB8(aC, bB);
    }
    // epilogue: k == KLEN-8
    LOADB8(bB, k + 4);
    LOADA8(aC, (kbeg + k) ^ pad);
    FMAB8(aC, bA);
    LOADA8(aC, (kbeg + k + 4) ^ pad);
    FMAB8(aC, bB);
}

// ---------------------------------------------------------------------------
// In-place attention + aggregation + bias + relu on acc[8][8]. (as round 8)
// ---------------------------------------------------------------------------
__device__ __forceinline__ void attnAgg(float acc[8][8],
                                        const float* __restrict__ avsP,
                                        const float* __restrict__ avdP,
                                        const float* __restrict__ bP, int rr)
{
    float4 s0 = *reinterpret_cast<const float4*>(avsP);
    float4 s1 = *reinterpret_cast<const float4*>(avsP + 4);
    float4 d0 = *reinterpret_cast<const float4*>(avdP);
    float4 d1 = *reinterpret_cast<const float4*>(avdP + 4);
    float als[8], ald[8];
    #pragma unroll
    for (int i = 0; i < 8; ++i) {
        als[i] = acc[i][0]*s0.x + acc[i][1]*s0.y + acc[i][2]*s0.z + acc[i][3]*s0.w
               + acc[i][4]*s1.x + acc[i][5]*s1.y + acc[i][6]*s1.z + acc[i][7]*s1.w;
        ald[i] = acc[i][0]*d0.x + acc[i][1]*d0.y + acc[i][2]*d0.z + acc[i][3]*d0.w
               + acc[i][4]*d1.x + acc[i][5]*d1.y + acc[i][6]*d1.z + acc[i][7]*d1.w;
    }
    #pragma unroll
    for (int m = 1; m <= 8; m <<= 1) {
        #pragma unroll
        for (int i = 0; i < 8; ++i) {
            als[i] += __shfl_xor(als[i], m);
            ald[i] += __shfl_xor(ald[i], m);
        }
    }
    float alsN = __shfl_down(als[0], 16);
    float accN[8];
    #pragma unroll
    for (int j = 0; j < 8; ++j) accN[j] = __shfl_down(acc[0][j], 16);

    float4 bb0 = *reinterpret_cast<const float4*>(bP);
    float4 bb1 = *reinterpret_cast<const float4*>(bP + 4);
    float bbv[8] = {bb0.x, bb0.y, bb0.z, bb0.w, bb1.x, bb1.y, bb1.z, bb1.w};
    const bool tail7 = (rr & 1);
    #pragma unroll
    for (int i = 0; i < 8; ++i) {
        float es = als[i] + ald[i];
        es = es > 0.f ? es : 0.2f * es;
        float aS = 1.f, aN = 0.f;
        if (!(tail7 && i == 7)) {
            float en = ((i < 7) ? als[i + 1] : alsN) + ald[i];
            en = en > 0.f ? en : 0.2f * en;
            float mx = fmaxf(es, en);
            float e1 = expf(es - mx), e2 = expf(en - mx);
            float den = e1 + e2;
            aS = e1 / den; aN = e2 / den;
        }
        #pragma unroll
        for (int j = 0; j < 8; ++j) {
            float nb = (i < 7) ? acc[i + 1][j] : accN[j];
            acc[i][j] = fmaxf(aS * acc[i][j] + aN * nb + bbv[j], 0.f);
        }
    }
}

// ---------------------------------------------------------------------------
// Pass 1: layer-0 forward for BN0 statistics only. (structure as round 8)
// ---------------------------------------------------------------------------
__global__ __launch_bounds__(128, 2)
void gat0_stats(const float* __restrict__ x, const float* __restrict__ W0,
                const float* __restrict__ as0, const float* __restrict__ ad0,
                const float* __restrict__ b0, float* __restrict__ pA0)
{
    __shared__ float xs[64][DD];
    __shared__ float bns[8][DD];

    const int tid = threadIdx.x;
    const int bid = blockIdx.x;
    const int rr = tid >> 4;
    const int cg = tid & 15;
    const int pad = (rr & 3) << 2;
    const size_t rb = (size_t)bid * 64;

    stageSwz<128>(xs, x + rb * DD);
    __syncthreads();

    float psum[HH][8], qsum[HH][8];
    #pragma unroll
    for (int h = 0; h < HH; ++h)
        #pragma unroll
        for (int j = 0; j < 8; ++j) { psum[h][j] = 0.f; qsum[h][j] = 0.f; }

    for (int h = 0; h < HH; ++h) {
        float acc[8][8];
        #pragma unroll
        for (int i = 0; i < 8; ++i)
            #pragma unroll
            for (int j = 0; j < 8; ++j) acc[i][j] = 0.f;

        gemm8x8<HD, 128>(xs, W0 + h * DD + cg * 8, 0, rr, pad, acc);
        attnAgg(acc, as0 + h * DD + cg * 8, ad0 + h * DD + cg * 8, b0 + h * DD + cg * 8, rr);

        #pragma unroll
        for (int i = 0; i < 8; ++i)
            #pragma unroll
            for (int j = 0; j < 8; ++j) {
                float o = acc[i][j];
                psum[h][j] += o; qsum[h][j] += o * o;
            }
    }

    for (int h = 0; h < HH; ++h) {
        __syncthreads();
        *reinterpret_cast<float4*>(&bns[rr][cg * 8]) =
            make_float4(psum[h][0], psum[h][1], psum[h][2], psum[h][3]);
        *reinterpret_cast<float4*>(&bns[rr][cg * 8 + 4]) =
            make_float4(psum[h][4], psum[h][5], psum[h][6], psum[h][7]);
        __syncthreads();
        float sv = 0.f;
        #pragma unroll
        for (int w = 0; w < 8; ++w) sv += bns[w][tid];
        __syncthreads();
        *reinterpret_cast<float4*>(&bns[rr][cg * 8]) =
            make_float4(qsum[h][0], qsum[h][1], qsum[h][2], qsum[h][3]);
        *reinterpret_cast<float4*>(&bns[rr][cg * 8 + 4]) =
            make_float4(qsum[h][4], qsum[h][5], qsum[h][6], qsum[h][7]);
        __syncthreads();
        float qv = 0.f;
        #pragma unroll
        for (int w = 0; w < 8; ++w) qv += bns[w][tid];
        size_t idx = ((size_t)bid * HD + h * DD + tid) * 2;
        pA0[idx] = sv; pA0[idx + 1] = qv;
    }
}

// ---------------------------------------------------------------------------
// Pass 3: recompute layer-0 (BN0 applied), interleaved layer-1 GEMM per head.
// K-SPLIT structure as round 8; gemm now B-prefetched.
// ---------------------------------------------------------------------------
__global__ __launch_bounds__(256, 2)
void gat1_recomp(const float* __restrict__ x, const float* __restrict__ W0,
                 const float* __restrict__ as0, const float* __restrict__ ad0,
                 const float* __restrict__ b0, const float* __restrict__ sc0,
                 const float* __restrict__ sh0, const float* __restrict__ W1,
                 const float* __restrict__ as1, const float* __restrict__ ad1,
                 const float* __restrict__ b1,
                 float* __restrict__ r1, float* __restrict__ pA1)
{
    __shared__ float xs[64][DD];
    __shared__ float hs[64][DD];
    __shared__ float bps[8][DD], bqs[8][DD];

    const int tid = threadIdx.x;
    const int bid = blockIdx.x;
    const int kh = tid >> 7;
    const int rr = (tid >> 4) & 7;
    const int cg = tid & 15;
    const int pad = (rr & 3) << 2;
    const size_t rb = (size_t)bid * 64;

    stageSwz<256>(xs, x + rb * DD);
    __syncthreads();

    float acc2[8][8];
    #pragma unroll
    for (int i = 0; i < 8; ++i)
        #pragma unroll
        for (int j = 0; j < 8; ++j) acc2[i][j] = 0.f;

    for (int h = 0; h < HH; ++h) {
        float acc[8][8];
        #pragma unroll
        for (int i = 0; i < 8; ++i)
            #pragma unroll
            for (int j = 0; j < 8; ++j) acc[i][j] = 0.f;

        gemm8x8<HD, 64>(xs, W0 + h * DD + cg * 8, kh * 64, rr, pad, acc);

        __syncthreads();
        if (kh == 1) {
            #pragma unroll
            for (int i = 0; i < 8; ++i) {
                int pc = (cg * 8) ^ pad;
                *reinterpret_cast<float4*>(&hs[rr * 8 + i][pc]) =
                    make_float4(acc[i][0], acc[i][1], acc[i][2], acc[i][3]);
                *reinterpret_cast<float4*>(&hs[rr * 8 + i][pc ^ 4]) =
                    make_float4(acc[i][4], acc[i][5], acc[i][6], acc[i][7]);
            }
        }
        __syncthreads();
        if (kh == 0) {
            #pragma unroll
            for (int i = 0; i < 8; ++i) {
                int pc = (cg * 8) ^ pad;
                float4 p0 = *reinterpret_cast<const float4*>(&hs[rr * 8 + i][pc]);
                float4 p1 = *reinterpret_cast<const float4*>(&hs[rr * 8 + i][pc ^ 4]);
                acc[i][0] += p0.x; acc[i][1] += p0.y; acc[i][2] += p0.z; acc[i][3] += p0.w;
                acc[i][4] += p1.x; acc[i][5] += p1.y; acc[i][6] += p1.z; acc[i][7] += p1.w;
            }
            attnAgg(acc, as0 + h * DD + cg * 8, ad0 + h * DD + cg * 8, b0 + h * DD + cg * 8, rr);
            float4 sc0a = *reinterpret_cast<const float4*>(&sc0[h * DD + cg * 8]);
            float4 sc0b = *reinterpret_cast<const float4*>(&sc0[h * DD + cg * 8 + 4]);
            float4 sh0a = *reinterpret_cast<const float4*>(&sh0[h * DD + cg * 8]);
            float4 sh0b = *reinterpret_cast<const float4*>(&sh0[h * DD + cg * 8 + 4]);
            float scv[8] = {sc0a.x, sc0a.y, sc0a.z, sc0a.w, sc0b.x, sc0b.y, sc0b.z, sc0b.w};
            float shv[8] = {sh0a.x, sh0a.y, sh0a.z, sh0a.w, sh0b.x, sh0b.y, sh0b.z, sh0b.w};
            #pragma unroll
            for (int i = 0; i < 8; ++i) {
                int pc = (cg * 8) ^ pad;
                float v0 = acc[i][0] * scv[0] + shv[0];
                float v1 = acc[i][1] * scv[1] + shv[1];
                float v2 = acc[i][2] * scv[2] + shv[2];
                float v3 = acc[i][3] * scv[3] + shv[3];
                float v4 = acc[i][4] * scv[4] + shv[4];
                float v5 = acc[i][5] * scv[5] + shv[5];
                float v6 = acc[i][6] * scv[6] + shv[6];
                float v7 = acc[i][7] * scv[7] + shv[7];
                *reinterpret_cast<float4*>(&hs[rr * 8 + i][pc]) = make_float4(v0, v1, v2, v3);
                *reinterpret_cast<float4*>(&hs[rr * 8 + i][pc ^ 4]) = make_float4(v4, v5, v6, v7);
            }
        }
        __syncthreads();

        gemm8x8<DD, 64>(hs, W1 + (size_t)(h * DD) * DD + cg * 8, kh * 64, rr, pad, acc2);
    }

    __syncthreads();
    if (kh == 1) {
        #pragma unroll
        for (int i = 0; i < 8; ++i) {
            int pc = (cg * 8) ^ pad;
            *reinterpret_cast<float4*>(&xs[rr * 8 + i][pc]) =
                make_float4(acc2[i][0], acc2[i][1], acc2[i][2], acc2[i][3]);
            *reinterpret_cast<float4*>(&xs[rr * 8 + i][pc ^ 4]) =
                make_float4(acc2[i][4], acc2[i][5], acc2[i][6], acc2[i][7]);
        }
    }
    __syncthreads();
    if (kh == 0) {
        #pragma unroll
        for (int i = 0; i < 8; ++i) {
            int pc = (cg * 8) ^ pad;
            float4 p0 = *reinterpret_cast<const float4*>(&xs[rr * 8 + i][pc]);
            float4 p1 = *reinterpret_cast<const float4*>(&xs[rr * 8 + i][pc ^ 4]);
            acc2[i][0] += p0.x; acc2[i][1] += p0.y; acc2[i][2] += p0.z; acc2[i][3] += p0.w;
            acc2[i][4] += p1.x; acc2[i][5] += p1.y; acc2[i][6] += p1.z; acc2[i][7] += p1.w;
        }
        attnAgg(acc2, as1 + cg * 8, ad1 + cg * 8, b1 + cg * 8, rr);

        float ps[8], pq[8];
        #pragma unroll
        for (int j = 0; j < 8; ++j) { ps[j] = 0.f; pq[j] = 0.f; }
        #pragma unroll
        for (int i = 0; i < 8; ++i) {
            *reinterpret_cast<float4*>(&r1[(rb + rr * 8 + i) * DD + cg * 8]) =
                make_float4(acc2[i][0], acc2[i][1], acc2[i][2], acc2[i][3]);
            *reinterpret_cast<float4*>(&r1[(rb + rr * 8 + i) * DD + cg * 8 + 4]) =
                make_float4(acc2[i][4], acc2[i][5], acc2[i][6], acc2[i][7]);
            #pragma unroll
            for (int j = 0; j < 8; ++j) { ps[j] += acc2[i][j]; pq[j] += acc2[i][j] * acc2[i][j]; }
        }
        *reinterpret_cast<float4*>(&bps[rr][cg * 8])     = make_float4(ps[0], ps[1], ps[2], ps[3]);
        *reinterpret_cast<float4*>(&bps[rr][cg * 8 + 4]) = make_float4(ps[4], ps[5], ps[6], ps[7]);
        *reinterpret_cast<float4*>(&bqs[rr][cg * 8])     = make_float4(pq[0], pq[1], pq[2], pq[3]);
        *reinterpret_cast<float4*>(&bqs[rr][cg * 8 + 4]) = make_float4(pq[4], pq[5], pq[6], pq[7]);
    }
    __syncthreads();
    if (tid < 128) {
        float s = 0.f, q = 0.f;
        #pragma unroll
        for (int w = 0; w < 8; ++w) { s += bps[w][tid]; q += bqs[w][tid]; }
        size_t idx = ((size_t)bid * DD + tid) * 2;
        pA1[idx] = s; pA1[idx + 1] = q;
    }
}

// ---------------------------------------------------------------------------
// BN stat reduction: per column, sum partials -> scale/shift
// ---------------------------------------------------------------------------
__global__ __launch_bounds__(256)
void bn_reduce(const float* __restrict__ pA, int nblk, int ncol, float invN,
               const float* __restrict__ g, const float* __restrict__ be,
               float* __restrict__ sc, float* __restrict__ sh)
{
    __shared__ float rs[256], rq[256];
    int col = blockIdx.x, tid = threadIdx.x;
    float s = 0.f, q = 0.f;
    for (int i = tid; i < nblk; i += 256) {
        size_t idx = ((size_t)i * ncol + col) * 2;
        s += pA[idx]; q += pA[idx + 1];
    }
    rs[tid] = s; rq[tid] = q;
    __syncthreads();
    for (int o = 128; o > 0; o >>= 1) {
        if (tid < o) { rs[tid] += rs[tid + o]; rq[tid] += rq[tid + o]; }
        __syncthreads();
    }
    if (tid == 0) {
        float mu  = rs[0] * invN;
        float var = fmaxf(rq[0] * invN - mu * mu, 0.f);
        float inv = 1.0f / sqrtf(var + EPSV);
        float scv = g[col] * inv;
        sc[col] = scv;
        sh[col] = be[col] - mu * scv;
    }
}

__global__ __launch_bounds__(128)
void compute_pn(const float* __restrict__ p, float* __restrict__ pn)
{
    __shared__ float rs[128];
    int t = threadIdx.x;
    float v = p[t];
    rs[t] = v * v;
    __syncthreads();
    for (int o = 64; o > 0; o >>= 1) {
        if (t < o) rs[t] += rs[t + o];
        __syncthreads();
    }
    float nrm = sqrtf(rs[0]) + 1e-16f;
    pn[t] = v / nrm;
}

// ---------------------------------------------------------------------------
// Pass 5: per-statement BN1 affine + score + top-8 + tanh-weighted relu mean
// + MLP 128->32->128
// ---------------------------------------------------------------------------
__global__ __launch_bounds__(128)
void pool_mlp(const float* __restrict__ r1, const float* __restrict__ sc1,
              const float* __restrict__ sh1, const float* __restrict__ pn,
              const float* __restrict__ mW1, const float* __restrict__ mb1,
              const float* __restrict__ mW2, const float* __restrict__ mb2,
              float* __restrict__ out)
{
    __shared__ float hf[16][136];
    __shared__ float sv[16];
    __shared__ float tv[16];
    __shared__ float pooled[128];
    __shared__ float y1[32];
    int tid = threadIdx.x;
    int sid = blockIdx.x;
    float scv = sc1[tid], shv = sh1[tid];
    const float* base = r1 + (size_t)sid * TT * DD;
    #pragma unroll
    for (int i = 0; i < 16; ++i)
        hf[i][tid] = base[i * DD + tid] * scv + shv;
    __syncthreads();

    {
        int r = tid >> 3, q = tid & 7;
        float s = 0.f;
        #pragma unroll
        for (int cc = 0; cc < 16; ++cc) {
            int c = q + cc * 8;
            s += hf[r][c] * pn[c];
        }
        s += __shfl_down(s, 4, 8);
        s += __shfl_down(s, 2, 8);
        s += __shfl_down(s, 1, 8);
        if (q == 0) sv[r] = s;
    }
    __syncthreads();

    if (tid < 16) {
        float si = sv[tid];
        int rank = 0;
        #pragma unroll
        for (int u = 0; u < 16; ++u) {
            float su = sv[u];
            rank += (su > si || (su == si && u < tid)) ? 1 : 0;
        }
        tv[tid] = (rank < 8) ? tanhf(si) : 0.f;
    }
    __syncthreads();

    {
        float a = 0.f;
        #pragma unroll
        for (int rr2 = 0; rr2 < 16; ++rr2)
            a += fmaxf(hf[rr2][tid] * tv[rr2], 0.f);
        pooled[tid] = a * 0.125f;
    }
    __syncthreads();

    {
        int j = tid >> 2, q = tid & 3;
        float a = 0.f;
        #pragma unroll
        for (int cc = 0; cc < 32; ++cc) {
            int c = q + cc * 4;
            a += pooled[c] * mW1[(size_t)c * 32 + j];
        }
        a += __shfl_down(a, 2, 4);
        a += __shfl_down(a, 1, 4);
        if (q == 0) y1[j] = fmaxf(a + mb1[j], 0.f);
    }
    __syncthreads();

    {
        float o = mb2[tid];
        #pragma unroll
        for (int j = 0; j < 32; ++j) o += y1[j] * mW2[j * 128 + tid];
        out[(size_t)sid * 128 + tid] = o;
    }
}

// ===========================================================================
extern "C" void kernel_launch(void* const* d_in, const int* in_sizes, int n_in,
                              void* d_out, int out_size, void* d_ws, size_t ws_size,
                              hipStream_t stream)
{
    (void)in_sizes; (void)n_in; (void)out_size; (void)ws_size;
    const float* x   = (const float*)d_in[0];
    const float* W0  = (const float*)d_in[1];
    const float* as0 = (const float*)d_in[2];
    const float* ad0 = (const float*)d_in[3];
    const float* b0  = (const float*)d_in[4];
    const float* g0  = (const float*)d_in[5];
    const float* be0 = (const float*)d_in[6];
    const float* W1  = (const float*)d_in[7];
    const float* as1 = (const float*)d_in[8];
    const float* ad1 = (const float*)d_in[9];
    const float* b1  = (const float*)d_in[10];
    const float* g1  = (const float*)d_in[11];
    const float* be1 = (const float*)d_in[12];
    const float* p   = (const float*)d_in[13];
    const float* mW1 = (const float*)d_in[14];
    const float* mb1 = (const float*)d_in[15];
    const float* mW2 = (const float*)d_in[16];
    const float* mb2 = (const float*)d_in[17];
    float* out = (float*)d_out;

    // ws layout (~151 MB; ws >= 156 MB proven by round-2 RECOMP pass)
    const size_t R1B  = (size_t)N_NODES * DD * 4;     // 134,217,728
    const size_t PA0B = 4096ull * HD * 2 * 4;         //  12,582,912
    const size_t PA1B = 4096ull * DD * 2 * 4;         //   4,194,304

    char* ws = (char*)d_ws;
    float* r1  = (float*)ws;
    float* pA0 = (float*)(ws + R1B);
    float* pA1 = (float*)(ws + R1B + PA0B);
    float* vec = (float*)(ws + R1B + PA0B + PA1B);
    float* sc0 = vec;            // 512 floats each slot
    float* sh0 = vec + 512;
    float* sc1 = vec + 1024;
    float* sh1 = vec + 1536;
    float* pn  = vec + 2048;

    const float invN = 1.0f / (float)N_NODES;

    gat0_stats<<<N_NODES / 64, 128, 0, stream>>>(x, W0, as0, ad0, b0, pA0);
    bn_reduce<<<HD, 256, 0, stream>>>(pA0, N_NODES / 64, HD, invN, g0, be0, sc0, sh0);
    compute_pn<<<1, 128, 0, stream>>>(p, pn);
    gat1_recomp<<<N_NODES / 64, 256, 0, stream>>>(x, W0, as0, ad0, b0, sc0, sh0,
                                                  W1, as1, ad1, b1, r1, pA1);
    bn_reduce<<<DD, 256, 0, stream>>>(pA1, N_NODES / 64, DD, invN, g1, be1, sc1, sh1);
    pool_mlp<<<SSTMT, 128, 0, stream>>>(r1, sc1, sh1, pn, mW1, mb1, mW2, mb2, out);
}

// Round 10
// 1232.378 us; speedup vs baseline: 1.4096x; 1.4096x over previous
//
#include <hip/hip_runtime.h>
#include <math.h>

// Problem constants (fixed by reference setup_inputs)
#define N_NODES 262144      // S*T
#define SSTMT   16384
#define TT      16
#define DD      128
#define HH      3
#define HD      384         // H*D
#define EPSV    1e-5f

// swizzle: rows {r, r+4, r+8, r+12} (one broadcast group) land in distinct
// 16B slots so the 4-distinct-address ds_read_b128 is conflict-free.
__device__ __forceinline__ int swzc(int row, int c) { return c ^ (((row >> 2) & 3) << 2); }

// ---------------------------------------------------------------------------
// stage a [64][128] fp32 tile from global into swizzled LDS (256 threads)
// ---------------------------------------------------------------------------
__device__ __forceinline__ void stageSwz(float (*dst)[DD], const float* __restrict__ src)
{
    const int tid = threadIdx.x;
    #pragma unroll
    for (int j = 0; j < 8; ++j) {
        int gi = j * 256 + tid;
        int row = gi >> 5;
        int c4 = (gi & 31) * 4;
        *reinterpret_cast<float4*>(&dst[row][swzc(row, c4)]) =
            *reinterpret_cast<const float4*>(&src[(size_t)row * DD + c4]);
    }
}

// ---------------------------------------------------------------------------
// GEMM K=128: acc[i][j] += A[rowBase+i][k] * B[k][cgg*8+j]
// A: swizzled LDS (4-way broadcast b128, conflict-free)
// B: GLOBAL (L1/L2-resident weights; 16 unique addrs = 256B coalesced/instr)
// micro-tile 4x8 -> acc 32 regs; fits 128-reg budget WITHOUT spills.
// ---------------------------------------------------------------------------
#define FMA8(s, bl, bh, i)                                    \
    acc[i][0] += s * bl.x; acc[i][1] += s * bl.y;             \
    acc[i][2] += s * bl.z; acc[i][3] += s * bl.w;             \
    acc[i][4] += s * bh.x; acc[i][5] += s * bh.y;             \
    acc[i][6] += s * bh.z; acc[i][7] += s * bh.w;

template<int BSTR>
__device__ __forceinline__ void gemm4x8(const float (*A)[DD], const float* __restrict__ Bg,
                                        int rowBase, int pad, float acc[4][8])
{
    const float* ar = &A[rowBase][0];
    const float* bp = Bg;
    #pragma unroll 2
    for (int k = 0; k < 128; k += 4) {
        int pc = k ^ pad;
        float4 a0 = *reinterpret_cast<const float4*>(ar + 0 * DD + pc);
        float4 a1 = *reinterpret_cast<const float4*>(ar + 1 * DD + pc);
        float4 a2 = *reinterpret_cast<const float4*>(ar + 2 * DD + pc);
        float4 a3 = *reinterpret_cast<const float4*>(ar + 3 * DD + pc);
        {
            float4 bl = *reinterpret_cast<const float4*>(bp);
            float4 bh = *reinterpret_cast<const float4*>(bp + 4);
            FMA8(a0.x, bl, bh, 0) FMA8(a1.x, bl, bh, 1)
            FMA8(a2.x, bl, bh, 2) FMA8(a3.x, bl, bh, 3)
        }
        {
            float4 bl = *reinterpret_cast<const float4*>(bp + BSTR);
            float4 bh = *reinterpret_cast<const float4*>(bp + BSTR + 4);
            FMA8(a0.y, bl, bh, 0) FMA8(a1.y, bl, bh, 1)
            FMA8(a2.y, bl, bh, 2) FMA8(a3.y, bl, bh, 3)
        }
        {
            float4 bl = *reinterpret_cast<const float4*>(bp + 2 * BSTR);
            float4 bh = *reinterpret_cast<const float4*>(bp + 2 * BSTR + 4);
            FMA8(a0.z, bl, bh, 0) FMA8(a1.z, bl, bh, 1)
            FMA8(a2.z, bl, bh, 2) FMA8(a3.z, bl, bh, 3)
        }
        {
            float4 bl = *reinterpret_cast<const float4*>(bp + 3 * BSTR);
            float4 bh = *reinterpret_cast<const float4*>(bp + 3 * BSTR + 4);
            FMA8(a0.w, bl, bh, 0) FMA8(a1.w, bl, bh, 1)
            FMA8(a2.w, bl, bh, 2) FMA8(a3.w, bl, bh, 3)
        }
        bp += 4 * BSTR;
    }
}

// ---------------------------------------------------------------------------
// In-place attention + aggregation + bias + relu on acc[4][8].
// Thread owns rows rowBase..rowBase+3, cols cgg*8..+7. Logit reduce over the
// 16-lane cgg group (shfl_xor 1..8). Each wave covers rows w*16..w*16+15
// (whole statements): neighbor for i==3 via shfl_down(16); rl==3,i==3 = tail.
// ---------------------------------------------------------------------------
__device__ __forceinline__ void attnAgg4(float acc[4][8],
                                         const float* __restrict__ avsP,
                                         const float* __restrict__ avdP,
                                         const float* __restrict__ bP, int rl)
{
    float4 s0 = *reinterpret_cast<const float4*>(avsP);
    float4 s1 = *reinterpret_cast<const float4*>(avsP + 4);
    float4 d0 = *reinterpret_cast<const float4*>(avdP);
    float4 d1 = *reinterpret_cast<const float4*>(avdP + 4);
    float als[4], ald[4];
    #pragma unroll
    for (int i = 0; i < 4; ++i) {
        als[i] = acc[i][0]*s0.x + acc[i][1]*s0.y + acc[i][2]*s0.z + acc[i][3]*s0.w
               + acc[i][4]*s1.x + acc[i][5]*s1.y + acc[i][6]*s1.z + acc[i][7]*s1.w;
        ald[i] = acc[i][0]*d0.x + acc[i][1]*d0.y + acc[i][2]*d0.z + acc[i][3]*d0.w
               + acc[i][4]*d1.x + acc[i][5]*d1.y + acc[i][6]*d1.z + acc[i][7]*d1.w;
    }
    #pragma unroll
    for (int m = 1; m <= 8; m <<= 1) {
        #pragma unroll
        for (int i = 0; i < 4; ++i) {
            als[i] += __shfl_xor(als[i], m);
            ald[i] += __shfl_xor(ald[i], m);
        }
    }
    float alsN = __shfl_down(als[0], 16);
    float accN[8];
    #pragma unroll
    for (int j = 0; j < 8; ++j) accN[j] = __shfl_down(acc[0][j], 16);

    float4 bb0 = *reinterpret_cast<const float4*>(bP);
    float4 bb1 = *reinterpret_cast<const float4*>(bP + 4);
    float bbv[8] = {bb0.x, bb0.y, bb0.z, bb0.w, bb1.x, bb1.y, bb1.z, bb1.w};
    const bool tail = (rl == 3);
    #pragma unroll
    for (int i = 0; i < 4; ++i) {
        float es = als[i] + ald[i];
        es = es > 0.f ? es : 0.2f * es;
        float aS = 1.f, aN = 0.f;
        if (!(tail && i == 3)) {
            float en = ((i < 3) ? als[i + 1] : alsN) + ald[i];
            en = en > 0.f ? en : 0.2f * en;
            float mx = fmaxf(es, en);
            float e1 = expf(es - mx), e2 = expf(en - mx);
            float den = e1 + e2;
            aS = e1 / den; aN = e2 / den;
        }
        #pragma unroll
        for (int j = 0; j < 8; ++j) {
            float nb = (i < 3) ? acc[i + 1][j] : accN[j];
            acc[i][j] = fmaxf(aS * acc[i][j] + aN * nb + bbv[j], 0.f);
        }
    }
}

// ---------------------------------------------------------------------------
// Pass 1: layer-0 forward for BN0 statistics only.
// Grid 4096 x 256 thr; 64 rows/block; 4x8 micro-tile; LDS 40KB -> 4 blk/CU;
// ~90 VGPR -> 4 waves/SIMD.
// ---------------------------------------------------------------------------
__global__ __launch_bounds__(256, 2)
void gat0_stats(const float* __restrict__ x, const float* __restrict__ W0,
                const float* __restrict__ as0, const float* __restrict__ ad0,
                const float* __restrict__ b0, float* __restrict__ pA0)
{
    __shared__ float xs[64][DD];
    __shared__ float bns[16][DD];

    const int tid = threadIdx.x;
    const int bid = blockIdx.x;
    const int rr = tid >> 4;          // 0..15 -> rows rr*4..rr*4+3
    const int cgg = tid & 15;         // cols cgg*8..+7
    const int rl = rr & 3;
    const int pad = rl << 2;
    const int rowBase = rr * 4;
    const size_t rb = (size_t)bid * 64;

    stageSwz(xs, x + rb * DD);
    __syncthreads();

    for (int h = 0; h < HH; ++h) {
        float acc[4][8];
        #pragma unroll
        for (int i = 0; i < 4; ++i)
            #pragma unroll
            for (int j = 0; j < 8; ++j) acc[i][j] = 0.f;

        gemm4x8<HD>(xs, W0 + h * DD + cgg * 8, rowBase, pad, acc);
        attnAgg4(acc, as0 + h * DD + cgg * 8, ad0 + h * DD + cgg * 8, b0 + h * DD + cgg * 8, rl);

        float ps[8], pq[8];
        #pragma unroll
        for (int j = 0; j < 8; ++j) { ps[j] = 0.f; pq[j] = 0.f; }
        #pragma unroll
        for (int i = 0; i < 4; ++i)
            #pragma unroll
            for (int j = 0; j < 8; ++j) {
                float o = acc[i][j];
                ps[j] += o; pq[j] += o * o;
            }

        // two-phase flush (sum, then sumsq) through bns
        __syncthreads();
        *reinterpret_cast<float4*>(&bns[rr][cgg * 8])     = make_float4(ps[0], ps[1], ps[2], ps[3]);
        *reinterpret_cast<float4*>(&bns[rr][cgg * 8 + 4]) = make_float4(ps[4], ps[5], ps[6], ps[7]);
        __syncthreads();
        float sv = 0.f;
        if (tid < 128) {
            #pragma unroll
            for (int w = 0; w < 16; ++w) sv += bns[w][tid];
        }
        __syncthreads();
        *reinterpret_cast<float4*>(&bns[rr][cgg * 8])     = make_float4(pq[0], pq[1], pq[2], pq[3]);
        *reinterpret_cast<float4*>(&bns[rr][cgg * 8 + 4]) = make_float4(pq[4], pq[5], pq[6], pq[7]);
        __syncthreads();
        if (tid < 128) {
            float qv = 0.f;
            #pragma unroll
            for (int w = 0; w < 16; ++w) qv += bns[w][tid];
            size_t idx = ((size_t)bid * HD + h * DD + tid) * 2;
            pA0[idx] = sv; pA0[idx + 1] = qv;
        }
    }
}

// ---------------------------------------------------------------------------
// Pass 3: recompute layer-0 (BN0 applied), interleaved layer-1 GEMM per head,
// layer-1 attention, write r1 + BN1 partials. Column-split: no K-split, no
// combine phases, 2 barriers/head. acc+acc2 = 64 regs -> no spills.
// LDS 64KB -> 2 blk/CU.
// ---------------------------------------------------------------------------
__global__ __launch_bounds__(256, 2)
void gat1_recomp(const float* __restrict__ x, const float* __restrict__ W0,
                 const float* __restrict__ as0, const float* __restrict__ ad0,
                 const float* __restrict__ b0, const float* __restrict__ sc0,
                 const float* __restrict__ sh0, const float* __restrict__ W1,
                 const float* __restrict__ as1, const float* __restrict__ ad1,
                 const float* __restrict__ b1,
                 float* __restrict__ r1, float* __restrict__ pA1)
{
    __shared__ float xs[64][DD];
    __shared__ float hs[64][DD];

    const int tid = threadIdx.x;
    const int bid = blockIdx.x;
    const int rr = tid >> 4;
    const int cgg = tid & 15;
    const int rl = rr & 3;
    const int pad = rl << 2;
    const int rowBase = rr * 4;
    const size_t rb = (size_t)bid * 64;

    stageSwz(xs, x + rb * DD);
    __syncthreads();

    float acc2[4][8];                  // layer-1 accumulator (K=384)
    #pragma unroll
    for (int i = 0; i < 4; ++i)
        #pragma unroll
        for (int j = 0; j < 8; ++j) acc2[i][j] = 0.f;

    for (int h = 0; h < HH; ++h) {
        // ---- layer-0 GEMM for head h ----
        float acc[4][8];
        #pragma unroll
        for (int i = 0; i < 4; ++i)
            #pragma unroll
            for (int j = 0; j < 8; ++j) acc[i][j] = 0.f;

        gemm4x8<HD>(xs, W0 + h * DD + cgg * 8, rowBase, pad, acc);
        attnAgg4(acc, as0 + h * DD + cgg * 8, ad0 + h * DD + cgg * 8, b0 + h * DD + cgg * 8, rl);

        // BN0 apply in regs
        {
            float4 sa = *reinterpret_cast<const float4*>(&sc0[h * DD + cgg * 8]);
            float4 sb = *reinterpret_cast<const float4*>(&sc0[h * DD + cgg * 8 + 4]);
            float4 ha = *reinterpret_cast<const float4*>(&sh0[h * DD + cgg * 8]);
            float4 hb = *reinterpret_cast<const float4*>(&sh0[h * DD + cgg * 8 + 4]);
            float scv[8] = {sa.x, sa.y, sa.z, sa.w, sb.x, sb.y, sb.z, sb.w};
            float shv[8] = {ha.x, ha.y, ha.z, ha.w, hb.x, hb.y, hb.z, hb.w};
            #pragma unroll
            for (int i = 0; i < 4; ++i)
                #pragma unroll
                for (int j = 0; j < 8; ++j)
                    acc[i][j] = acc[i][j] * scv[j] + shv[j];
        }

        __syncthreads();               // prev head's GEMM1 readers of hs done
        {
            int pcA = (cgg * 8) ^ pad;
            int pcB = pcA ^ 4;
            #pragma unroll
            for (int i = 0; i < 4; ++i) {
                *reinterpret_cast<float4*>(&hs[rowBase + i][pcA]) =
                    make_float4(acc[i][0], acc[i][1], acc[i][2], acc[i][3]);
                *reinterpret_cast<float4*>(&hs[rowBase + i][pcB]) =
                    make_float4(acc[i][4], acc[i][5], acc[i][6], acc[i][7]);
            }
        }
        __syncthreads();

        // ---- layer-1 partial GEMM over k chunk [h*128, h*128+128) ----
        gemm4x8<DD>(hs, W1 + (size_t)(h * DD) * DD + cgg * 8, rowBase, pad, acc2);
    }

    // ---- layer-1 attention (in regs) + outputs ----
    attnAgg4(acc2, as1 + cgg * 8, ad1 + cgg * 8, b1 + cgg * 8, rl);

    float ps[8], pq[8];
    #pragma unroll
    for (int j = 0; j < 8; ++j) { ps[j] = 0.f; pq[j] = 0.f; }
    #pragma unroll
    for (int i = 0; i < 4; ++i) {
        *reinterpret_cast<float4*>(&r1[(rb + rowBase + i) * DD + cgg * 8]) =
            make_float4(acc2[i][0], acc2[i][1], acc2[i][2], acc2[i][3]);
        *reinterpret_cast<float4*>(&r1[(rb + rowBase + i) * DD + cgg * 8 + 4]) =
            make_float4(acc2[i][4], acc2[i][5], acc2[i][6], acc2[i][7]);
        #pragma unroll
        for (int j = 0; j < 8; ++j) { ps[j] += acc2[i][j]; pq[j] += acc2[i][j] * acc2[i][j]; }
    }

    // flush BN1 partials through xs alias (xs dead after last GEMM0)
    float (*bns)[DD] = xs;
    __syncthreads();
    *reinterpret_cast<float4*>(&bns[rr][cgg * 8])     = make_float4(ps[0], ps[1], ps[2], ps[3]);
    *reinterpret_cast<float4*>(&bns[rr][cgg * 8 + 4]) = make_float4(ps[4], ps[5], ps[6], ps[7]);
    __syncthreads();
    float sv = 0.f;
    if (tid < 128) {
        #pragma unroll
        for (int w = 0; w < 16; ++w) sv += bns[w][tid];
    }
    __syncthreads();
    *reinterpret_cast<float4*>(&bns[rr][cgg * 8])     = make_float4(pq[0], pq[1], pq[2], pq[3]);
    *reinterpret_cast<float4*>(&bns[rr][cgg * 8 + 4]) = make_float4(pq[4], pq[5], pq[6], pq[7]);
    __syncthreads();
    if (tid < 128) {
        float qv = 0.f;
        #pragma unroll
        for (int w = 0; w < 16; ++w) qv += bns[w][tid];
        size_t idx = ((size_t)bid * DD + tid) * 2;
        pA1[idx] = sv; pA1[idx + 1] = qv;
    }
}

// ---------------------------------------------------------------------------
// BN stat reduction: per column, sum partials -> scale/shift
// ---------------------------------------------------------------------------
__global__ __launch_bounds__(256)
void bn_reduce(const float* __restrict__ pA, int nblk, int ncol, float invN,
               const float* __restrict__ g, const float* __restrict__ be,
               float* __restrict__ sc, float* __restrict__ sh)
{
    __shared__ float rs[256], rq[256];
    int col = blockIdx.x, tid = threadIdx.x;
    float s = 0.f, q = 0.f;
    for (int i = tid; i < nblk; i += 256) {
        size_t idx = ((size_t)i * ncol + col) * 2;
        s += pA[idx]; q += pA[idx + 1];
    }
    rs[tid] = s; rq[tid] = q;
    __syncthreads();
    for (int o = 128; o > 0; o >>= 1) {
        if (tid < o) { rs[tid] += rs[tid + o]; rq[tid] += rq[tid + o]; }
        __syncthreads();
    }
    if (tid == 0) {
        float mu  = rs[0] * invN;
        float var = fmaxf(rq[0] * invN - mu * mu, 0.f);
        float inv = 1.0f / sqrtf(var + EPSV);
        float scv = g[col] * inv;
        sc[col] = scv;
        sh[col] = be[col] - mu * scv;
    }
}

__global__ __launch_bounds__(128)
void compute_pn(const float* __restrict__ p, float* __restrict__ pn)
{
    __shared__ float rs[128];
    int t = threadIdx.x;
    float v = p[t];
    rs[t] = v * v;
    __syncthreads();
    for (int o = 64; o > 0; o >>= 1) {
        if (t < o) rs[t] += rs[t + o];
        __syncthreads();
    }
    float nrm = sqrtf(rs[0]) + 1e-16f;
    pn[t] = v / nrm;
}

// ---------------------------------------------------------------------------
// Pass 5: per-statement BN1 affine + score + top-8 + tanh-weighted relu mean
// + MLP 128->32->128
// ---------------------------------------------------------------------------
__global__ __launch_bounds__(128)
void pool_mlp(const float* __restrict__ r1, const float* __restrict__ sc1,
              const float* __restrict__ sh1, const float* __restrict__ pn,
              const float* __restrict__ mW1, const float* __restrict__ mb1,
              const float* __restrict__ mW2, const float* __restrict__ mb2,
              float* __restrict__ out)
{
    __shared__ float hf[16][136];
    __shared__ float sv[16];
    __shared__ float tv[16];
    __shared__ float pooled[128];
    __shared__ float y1[32];
    int tid = threadIdx.x;
    int sid = blockIdx.x;
    float scv = sc1[tid], shv = sh1[tid];
    const float* base = r1 + (size_t)sid * TT * DD;
    #pragma unroll
    for (int i = 0; i < 16; ++i)
        hf[i][tid] = base[i * DD + tid] * scv + shv;
    __syncthreads();

    {
        int r = tid >> 3, q = tid & 7;
        float s = 0.f;
        #pragma unroll
        for (int cc = 0; cc < 16; ++cc) {
            int c = q + cc * 8;
            s += hf[r][c] * pn[c];
        }
        s += __shfl_down(s, 4, 8);
        s += __shfl_down(s, 2, 8);
        s += __shfl_down(s, 1, 8);
        if (q == 0) sv[r] = s;
    }
    __syncthreads();

    if (tid < 16) {
        float si = sv[tid];
        int rank = 0;
        #pragma unroll
        for (int u = 0; u < 16; ++u) {
            float su = sv[u];
            rank += (su > si || (su == si && u < tid)) ? 1 : 0;
        }
        tv[tid] = (rank < 8) ? tanhf(si) : 0.f;
    }
    __syncthreads();

    {
        float a = 0.f;
        #pragma unroll
        for (int rr2 = 0; rr2 < 16; ++rr2)
            a += fmaxf(hf[rr2][tid] * tv[rr2], 0.f);
        pooled[tid] = a * 0.125f;
    }
    __syncthreads();

    {
        int j = tid >> 2, q = tid & 3;
        float a = 0.f;
        #pragma unroll
        for (int cc = 0; cc < 32; ++cc) {
            int c = q + cc * 4;
            a += pooled[c] * mW1[(size_t)c * 32 + j];
        }
        a += __shfl_down(a, 2, 4);
        a += __shfl_down(a, 1, 4);
        if (q == 0) y1[j] = fmaxf(a + mb1[j], 0.f);
    }
    __syncthreads();

    {
        float o = mb2[tid];
        #pragma unroll
        for (int j = 0; j < 32; ++j) o += y1[j] * mW2[j * 128 + tid];
        out[(size_t)sid * 128 + tid] = o;
    }
}

// ===========================================================================
extern "C" void kernel_launch(void* const* d_in, const int* in_sizes, int n_in,
                              void* d_out, int out_size, void* d_ws, size_t ws_size,
                              hipStream_t stream)
{
    (void)in_sizes; (void)n_in; (void)out_size; (void)ws_size;
    const float* x   = (const float*)d_in[0];
    const float* W0  = (const float*)d_in[1];
    const float* as0 = (const float*)d_in[2];
    const float* ad0 = (const float*)d_in[3];
    const float* b0  = (const float*)d_in[4];
    const float* g0  = (const float*)d_in[5];
    const float* be0 = (const float*)d_in[6];
    const float* W1  = (const float*)d_in[7];
    const float* as1 = (const float*)d_in[8];
    const float* ad1 = (const float*)d_in[9];
    const float* b1  = (const float*)d_in[10];
    const float* g1  = (const float*)d_in[11];
    const float* be1 = (const float*)d_in[12];
    const float* p   = (const float*)d_in[13];
    const float* mW1 = (const float*)d_in[14];
    const float* mb1 = (const float*)d_in[15];
    const float* mW2 = (const float*)d_in[16];
    const float* mb2 = (const float*)d_in[17];
    float* out = (float*)d_out;

    // ws layout (~151 MB; ws >= 156 MB proven by round-2 RECOMP pass)
    const size_t R1B  = (size_t)N_NODES * DD * 4;     // 134,217,728
    const size_t PA0B = 4096ull * HD * 2 * 4;         //  12,582,912
    const size_t PA1B = 4096ull * DD * 2 * 4;         //   4,194,304

    char* ws = (char*)d_ws;
    float* r1  = (float*)ws;
    float* pA0 = (float*)(ws + R1B);
    float* pA1 = (float*)(ws + R1B + PA0B);
    float* vec = (float*)(ws + R1B + PA0B + PA1B);
    float* sc0 = vec;            // 512 floats each slot
    float* sh0 = vec + 512;
    float* sc1 = vec + 1024;
    float* sh1 = vec + 1536;
    float* pn  = vec + 2048;

    const float invN = 1.0f / (float)N_NODES;

    gat0_stats<<<N_NODES / 64, 256, 0, stream>>>(x, W0, as0, ad0, b0, pA0);
    bn_reduce<<<HD, 256, 0, stream>>>(pA0, N_NODES / 64, HD, invN, g0, be0, sc0, sh0);
    compute_pn<<<1, 128, 0, stream>>>(p, pn);
    gat1_recomp<<<N_NODES / 64, 256, 0, stream>>>(x, W0, as0, ad0, b0, sc0, sh0,
                                                  W1, as1, ad1, b1, r1, pA1);
    bn_reduce<<<DD, 256, 0, stream>>>(pA1, N_NODES / 64, DD, invN, g1, be1, sc1, sh1);
    pool_mlp<<<SSTMT, 128, 0, stream>>>(r1, sc1, sh1, pn, mW1, mb1, mW2, mb2, out);
}